// Round 12
// baseline (497.194 us; speedup 1.0000x reference)
//
#include <hip/hip_runtime.h>
#include <hip/hip_bf16.h>

#define DIN 128
#define HID 32
#define EPS 1e-5f
#define BUCK 256          // nodes per bucket
#define BSH 8
#define CHKC 256          // edge chunks
#define SCAP 13000        // staged records per chunk (chunk=12500 for E=3.2M)
#define RCAP 12288        // staged esort entries per bucket (mean 8192, +45 sigma)
#define WSC 16384.0f      // 2^14 fixed-point scale for w sums
#define WSI 6.103515625e-5f  // 2^-14

typedef unsigned int u32;
typedef unsigned short u16;
typedef unsigned long long u64;

// extract bf16 half of a packed u32 (hi=0 -> low 16 bits = even channel) as float
__device__ __forceinline__ float bfx(u32 v, int hi) {
    return __uint_as_float(hi ? (v & 0xffff0000u) : (v << 16));
}

__device__ __forceinline__ u16 f2bf(float f) {
    __hip_bfloat16 h = __float2bfloat16(f);
    return *reinterpret_cast<u16*>(&h);
}

// ---------------- zero BN stats ----------------
__global__ void init_stats(float* __restrict__ stats) {
    if (threadIdx.x < 192) stats[threadIdx.x] = 0.f;
}

// ---------------- phase A: per-(chunk) LDS bucket histogram ----------------
__global__ __launch_bounds__(1024) void bucket_count(
        const int* __restrict__ col, int E, u32* __restrict__ cpart2, int nbuck) {
    __shared__ u32 cnt[512];
    int c = blockIdx.x;
    for (int i = threadIdx.x; i < 512; i += 1024) cnt[i] = 0;
    __syncthreads();
    int chunk = (E + CHKC - 1) / CHKC;
    int e0 = c * chunk, e1 = e0 + chunk;
    if (e1 > E) e1 = E;
    for (int e = e0 + threadIdx.x; e < e1; e += 1024)
        atomicAdd(&cnt[col[e] >> BSH], 1u);
    __syncthreads();
    for (int i = threadIdx.x; i < nbuck; i += 1024)
        cpart2[i * CHKC + c] = cnt[i];
}

// ---------------- exclusive scan (for the (bucket,chunk) cells) ----------------
__global__ void scan_blocks(int* __restrict__ data, int* __restrict__ bsum, int n) {
    __shared__ int s[256];
    int i = blockIdx.x * 256 + threadIdx.x;
    int v = (i < n) ? data[i] : 0;
    s[threadIdx.x] = v;
    __syncthreads();
    for (int off = 1; off < 256; off <<= 1) {
        int t = (threadIdx.x >= off) ? s[threadIdx.x - off] : 0;
        __syncthreads();
        s[threadIdx.x] += t;
        __syncthreads();
    }
    if (i < n) data[i] = s[threadIdx.x] - v;  // exclusive
    if (threadIdx.x == 255) bsum[blockIdx.x] = s[255];
}

__global__ void scan_tops(int* __restrict__ bsum, int nb) {
    __shared__ int s[512];
    int v = (threadIdx.x < nb) ? bsum[threadIdx.x] : 0;
    s[threadIdx.x] = v;
    __syncthreads();
    for (int off = 1; off < 512; off <<= 1) {
        int t = (threadIdx.x >= off) ? s[threadIdx.x - off] : 0;
        __syncthreads();
        s[threadIdx.x] += t;
        __syncthreads();
    }
    if (threadIdx.x < nb) bsum[threadIdx.x] = s[threadIdx.x] - v;  // exclusive
}

__global__ void scan_addback(int* __restrict__ data, const int* __restrict__ bsum,
                             int n, int E) {
    int i = blockIdx.x * 256 + threadIdx.x;
    if (i < n) data[i] += bsum[blockIdx.x];
    if (i == n) data[n] = E;  // sentinel
}

// ---------------- phase C: LDS counting-sort scatter (all global writes coalesced) --
// record u64 = w_bits<<32 | src<<BSH | col_in_bucket.
__global__ __launch_bounds__(1024) void bucket_scatter(
        const int* __restrict__ row, const int* __restrict__ col,
        const float* __restrict__ w, const u32* __restrict__ cpart2,
        u64* __restrict__ rec8, int E, int nbuck) {
    __shared__ u64 srec[SCAP];                    // 104KB
    __shared__ u32 lcnt[512], lbase[512], lcur[512], cellb[512];
    int c = blockIdx.x, tid = threadIdx.x;
    int chunk = (E + CHKC - 1) / CHKC;
    int e0 = c * chunk, e1 = e0 + chunk;
    if (e1 > E) e1 = E;
    for (int i = tid; i < 512; i += 1024) lcnt[i] = 0;
    __syncthreads();
    if (chunk <= SCAP) {
        for (int e = e0 + tid; e < e1; e += 1024)
            atomicAdd(&lcnt[col[e] >> BSH], 1u);
        __syncthreads();
        if (tid < 512) lbase[tid] = lcnt[tid];
        __syncthreads();
        for (int off = 1; off < 512; off <<= 1) {
            u32 t = 0;
            if (tid < 512 && tid >= off) t = lbase[tid - off];
            __syncthreads();
            if (tid < 512) lbase[tid] += t;
            __syncthreads();
        }
        if (tid < 512) {
            lcur[tid] = lbase[tid] - lcnt[tid];  // exclusive base
            cellb[tid] = (tid < nbuck) ? cpart2[tid * CHKC + c] : 0;
        }
        __syncthreads();
        for (int e = e0 + tid; e < e1; e += 1024) {
            int cc = col[e];
            int b = cc >> BSH;
            u32 p = atomicAdd(&lcur[b], 1u);
            srec[p] = ((u64)__float_as_uint(w[e]) << 32) |
                      ((u64)(u32)row[e] << BSH) | (u64)(u32)(cc & (BUCK - 1));
        }
        __syncthreads();
        int wv = tid >> 6, lane = tid & 63;
        for (int b = wv; b < nbuck; b += 16) {
            int len = (int)lcnt[b];
            int s = (int)(lbase[b] - lcnt[b]);
            u64* dst = rec8 + cellb[b];
            for (int j = lane; j < len; j += 64) dst[j] = srec[s + j];
        }
    } else {
        if (tid < 512) lcur[tid] = (tid < nbuck) ? cpart2[tid * CHKC + c] : 0;
        __syncthreads();
        for (int e = e0 + tid; e < e1; e += 1024) {
            int cc = col[e];
            int b = cc >> BSH;
            u32 pos = atomicAdd(&lcur[b], 1u);
            rec8[pos] = ((u64)__float_as_uint(w[e]) << 32) |
                        ((u64)(u32)row[e] << BSH) | (u64)(u32)(cc & (BUCK - 1));
        }
    }
}

// ---------------- phase D+F fused: hist -> rowptr/dinv -> rank -> esort ----------------
// RACE FIX (R11): esort entry stores bf16(w * dinv[dst]) — dst is in THIS bucket
// (dl[i] computed by this block in pass 1), so no cross-bucket dinv read exists.
// The dinv[src] factor is folded into hbf instead (gemm kernels pre-scale by dinv).
// Bonus: deletes E random dinv[src] gathers from this kernel.
__global__ __launch_bounds__(1024) void bucket_finalize(
        const u64* __restrict__ rec8, const u32* __restrict__ cpart2,
        int* __restrict__ rowptr, float* __restrict__ dinv,
        u32* __restrict__ esort, int E, int N, int nbuck) {
    __shared__ u32 stage[RCAP];   // 48KB
    __shared__ u64 cw[BUCK];      // 2KB
    __shared__ int sp[BUCK];
    __shared__ u32 cnt[BUCK];
    __shared__ float dl[BUCK];
    __shared__ int baseR[BUCK];
    int b = blockIdx.x, tid = threadIdx.x;
    int k0 = (int)cpart2[b * CHKC];
    int k1 = (b + 1 < nbuck) ? (int)cpart2[(b + 1) * CHKC] : E;
    for (int i = tid; i < BUCK; i += 1024) cw[i] = 0ull;
    __syncthreads();
    for (int k = k0 + tid; k < k1; k += 1024) {
        u64 v = rec8[k];
        int i = (int)((u32)v & (BUCK - 1));
        float wv = __uint_as_float((u32)(v >> 32));
        atomicAdd(&cw[i], (1ull << 32) | (u64)(u32)(wv * WSC + 0.5f));
    }
    __syncthreads();
    if (tid < BUCK) sp[tid] = (int)(cw[tid] >> 32);
    __syncthreads();
    for (int off = 1; off < BUCK; off <<= 1) {
        int t = 0;
        if (tid < BUCK && tid >= off) t = sp[tid - off];
        __syncthreads();
        if (tid < BUCK) sp[tid] += t;
        __syncthreads();
    }
    if (tid < BUCK) {
        int g = (b << BSH) + tid;
        int own = (int)(cw[tid] >> 32);
        float dv = rsqrtf(1.0f + (float)(u32)cw[tid] * WSI);  // +1 self loop
        cnt[tid] = 0;
        baseR[tid] = sp[tid] - own;
        dl[tid] = dv;
        if (g < N) {
            rowptr[g] = k0 + sp[tid] - own;
            dinv[g] = dv;
        }
    }
    if (b == nbuck - 1 && tid == 0) rowptr[N] = E;
    __syncthreads();
    for (int k = k0 + tid; k < k1; k += 1024) {
        u64 v = rec8[k];  // L2-hot re-read
        u32 lo = (u32)v;
        int i = (int)(lo & (BUCK - 1));
        int src = (int)(lo >> BSH);
        u32 rk = atomicAdd(&cnt[i], 1u);
        float nv = __uint_as_float((u32)(v >> 32)) * dl[i];  // w * dinv[dst] ONLY
        u32 entry = ((u32)src << 15) | (u32)f2bf(nv);
        int off = baseR[i] + (int)rk;
        if (off < RCAP) stage[off] = entry;
        else esort[k0 + off] = entry;  // overflow guard (statistically unreachable)
    }
    __syncthreads();
    int len = k1 - k0;
    int lim = len < RCAP ? len : RCAP;
    for (int j = tid; j < lim; j += 1024) esort[k0 + j] = stage[j];
}

// ---------------- layer-0 GEMM (x fp32 -> hbf = dinv[node] * (x@W), node-major) -----
__global__ __launch_bounds__(256) void gemm_din(const float* __restrict__ x,
                                                const float* __restrict__ W,
                                                const float* __restrict__ dinv,
                                                u16* __restrict__ hbf, int n) {
    __shared__ float xl[32][132];
    __shared__ float Wl[DIN * HID];  // k-major
    int t = threadIdx.x;
    for (int i = t; i < DIN * HID; i += 256) Wl[i] = W[i];
    int nbase = blockIdx.x * 32;
    int nrows = n - nbase; if (nrows > 32) nrows = 32;
    for (int i = t; i < nrows * 32; i += 256) {
        int nn = i >> 5, k4 = (i & 31) * 4;
        *(float4*)&xl[nn][k4] = *(const float4*)&x[(size_t)(nbase + nn) * DIN + k4];
    }
    __syncthreads();
    int chq = t & 7, nn = t >> 3;
    if (nn >= nrows) return;
    float ax = 0.f, ay = 0.f, az = 0.f, aw = 0.f;
#pragma unroll 8
    for (int k = 0; k < DIN; ++k) {
        float xv = xl[nn][k];
        float4 wv = *(float4*)&Wl[k * HID + chq * 4];
        ax += xv * wv.x; ay += xv * wv.y; az += xv * wv.z; aw += xv * wv.w;
    }
    int node = nbase + nn;
    float dv = dinv[node];
    ax *= dv; ay *= dv; az *= dv; aw *= dv;
    u64 pk = (u64)f2bf(ax) | ((u64)f2bf(ay) << 16) | ((u64)f2bf(az) << 32) |
             ((u64)f2bf(aw) << 48);
    *(u64*)&hbf[(size_t)node * 32 + chq * 4] = pk;
}

// ---------------- hidden GEMM, fused BN+ReLU; hbf = dinv * (relu(bn(agg))@W) --------
__global__ __launch_bounds__(256) void gemm_hid_bn(
        const float* __restrict__ aS, const float* __restrict__ W,
        const float* __restrict__ stats, const float* __restrict__ g,
        const float* __restrict__ be, const float* __restrict__ dinv,
        u16* __restrict__ hbf, int n, float invN) {
    __shared__ float xl[32][36];
    __shared__ float Wl[HID * HID];  // k-major
    __shared__ float sc[HID], sh[HID];
    int t = threadIdx.x;
    for (int i = t; i < HID * HID; i += 256) Wl[i] = W[i];
    if (t < HID) {
        float mu = stats[t] * invN;
        float var = stats[32 + t] * invN - mu * mu;
        float s = rsqrtf(var + EPS) * g[t];
        sc[t] = s;
        sh[t] = be[t] - mu * s;
    }
    int nbase = blockIdx.x * 32;
    int nrows = n - nbase; if (nrows > 32) nrows = 32;
    for (int i = t; i < nrows * 8; i += 256) {
        int nn = i >> 3, q = i & 7;
        *(float4*)&xl[nn][q * 4] =
            *(const float4*)&aS[(size_t)(nbase + nn) * 32 + q * 4];
    }
    __syncthreads();
    int chq = t & 7, nn = t >> 3;
    if (nn >= nrows) return;
    float ax = 0.f, ay = 0.f, az = 0.f, aw = 0.f;
#pragma unroll
    for (int k = 0; k < HID; ++k) {
        float v = fmaxf(xl[nn][k] * sc[k] + sh[k], 0.f);
        float4 wv = *(float4*)&Wl[k * HID + chq * 4];
        ax += v * wv.x; ay += v * wv.y; az += v * wv.z; aw += v * wv.w;
    }
    int node = nbase + nn;
    float dv = dinv[node];
    ax *= dv; ay *= dv; az *= dv; aw *= dv;
    u64 pk = (u64)f2bf(ax) | ((u64)f2bf(ay) << 16) | ((u64)f2bf(az) << 32) |
             ((u64)f2bf(aw) << 48);
    *(u64*)&hbf[(size_t)node * 32 + chq * 4] = pk;
}

// ---------------- fused full-width CSR gather, v3 ----------------
// h2 rows are PRE-SCALED by dinv[src]; entry norm = w * dinv[dst]; self term uses
// s = dinv[node] (one factor, the other is inside hbf). 4 lanes/node, lane q owns
// 8 channels via ONE uint4 load per edge; esort deduped via width-4 shfl.
template<int RELU>
__global__ __launch_bounds__(256) void gather_t(
        const u32* __restrict__ h2, const int* __restrict__ rowptr,
        const u32* __restrict__ esort, const float* __restrict__ dinv,
        const float* __restrict__ b, float* __restrict__ out, int n) {
    int q = threadIdx.x & 3;
    int node = blockIdx.x * 64 + (threadIdx.x >> 2);
    if (node >= n) return;
    float s = dinv[node];   // hbf already carries one dinv factor
    uint4 hv = *(const uint4*)&h2[(size_t)node * 16 + q * 4];
    float acc[8];
    acc[0] = s * bfx(hv.x, 0) + b[q * 8 + 0];
    acc[1] = s * bfx(hv.x, 1) + b[q * 8 + 1];
    acc[2] = s * bfx(hv.y, 0) + b[q * 8 + 2];
    acc[3] = s * bfx(hv.y, 1) + b[q * 8 + 3];
    acc[4] = s * bfx(hv.z, 0) + b[q * 8 + 4];
    acc[5] = s * bfx(hv.z, 1) + b[q * 8 + 5];
    acc[6] = s * bfx(hv.w, 0) + b[q * 8 + 6];
    acc[7] = s * bfx(hv.w, 1) + b[q * 8 + 7];
    int j = rowptr[node], end = rowptr[node + 1];
    for (; j + 4 <= end; j += 4) {
        u32 em = esort[j + q];                 // coalesced: 4 lanes, 4 entries
        u32 e0 = __shfl(em, 0, 4);
        u32 e1 = __shfl(em, 1, 4);
        u32 e2 = __shfl(em, 2, 4);
        u32 e3 = __shfl(em, 3, 4);
        uint4 v0 = *(const uint4*)&h2[(size_t)(e0 >> 15) * 16 + q * 4];
        uint4 v1 = *(const uint4*)&h2[(size_t)(e1 >> 15) * 16 + q * 4];
        uint4 v2 = *(const uint4*)&h2[(size_t)(e2 >> 15) * 16 + q * 4];
        uint4 v3 = *(const uint4*)&h2[(size_t)(e3 >> 15) * 16 + q * 4];
        float n0 = __uint_as_float((e0 & 0x7fffu) << 16);
        float n1 = __uint_as_float((e1 & 0x7fffu) << 16);
        float n2 = __uint_as_float((e2 & 0x7fffu) << 16);
        float n3 = __uint_as_float((e3 & 0x7fffu) << 16);
        acc[0] += n0 * bfx(v0.x, 0); acc[1] += n0 * bfx(v0.x, 1);
        acc[2] += n0 * bfx(v0.y, 0); acc[3] += n0 * bfx(v0.y, 1);
        acc[4] += n0 * bfx(v0.z, 0); acc[5] += n0 * bfx(v0.z, 1);
        acc[6] += n0 * bfx(v0.w, 0); acc[7] += n0 * bfx(v0.w, 1);
        acc[0] += n1 * bfx(v1.x, 0); acc[1] += n1 * bfx(v1.x, 1);
        acc[2] += n1 * bfx(v1.y, 0); acc[3] += n1 * bfx(v1.y, 1);
        acc[4] += n1 * bfx(v1.z, 0); acc[5] += n1 * bfx(v1.z, 1);
        acc[6] += n1 * bfx(v1.w, 0); acc[7] += n1 * bfx(v1.w, 1);
        acc[0] += n2 * bfx(v2.x, 0); acc[1] += n2 * bfx(v2.x, 1);
        acc[2] += n2 * bfx(v2.y, 0); acc[3] += n2 * bfx(v2.y, 1);
        acc[4] += n2 * bfx(v2.z, 0); acc[5] += n2 * bfx(v2.z, 1);
        acc[6] += n2 * bfx(v2.w, 0); acc[7] += n2 * bfx(v2.w, 1);
        acc[0] += n3 * bfx(v3.x, 0); acc[1] += n3 * bfx(v3.x, 1);
        acc[2] += n3 * bfx(v3.y, 0); acc[3] += n3 * bfx(v3.y, 1);
        acc[4] += n3 * bfx(v3.z, 0); acc[5] += n3 * bfx(v3.z, 1);
        acc[6] += n3 * bfx(v3.w, 0); acc[7] += n3 * bfx(v3.w, 1);
    }
    for (; j < end; ++j) {
        u32 ed = esort[j];
        uint4 v = *(const uint4*)&h2[(size_t)(ed >> 15) * 16 + q * 4];
        float nv = __uint_as_float((ed & 0x7fffu) << 16);
        acc[0] += nv * bfx(v.x, 0); acc[1] += nv * bfx(v.x, 1);
        acc[2] += nv * bfx(v.y, 0); acc[3] += nv * bfx(v.y, 1);
        acc[4] += nv * bfx(v.z, 0); acc[5] += nv * bfx(v.z, 1);
        acc[6] += nv * bfx(v.w, 0); acc[7] += nv * bfx(v.w, 1);
    }
    if (RELU) {
#pragma unroll
        for (int i = 0; i < 8; ++i) acc[i] = fmaxf(acc[i], 0.f);
    }
    float4 o0 = {acc[0], acc[1], acc[2], acc[3]};
    float4 o1 = {acc[4], acc[5], acc[6], acc[7]};
    *(float4*)&out[(size_t)node * 32 + q * 8] = o0;
    *(float4*)&out[(size_t)node * 32 + q * 8 + 4] = o1;
}

// ---------------- BN stats reduce (node-major agg) ----------------
__global__ void bn_reduce(const float* __restrict__ aS, float* __restrict__ stats, int n) {
    __shared__ float s1[256], s2[256];
    int ch = threadIdx.x & 31, rg = threadIdx.x >> 5;
    float a = 0.f, b = 0.f;
    for (int node = blockIdx.x * 8 + rg; node < n; node += gridDim.x * 8) {
        float v = aS[(size_t)node * 32 + ch];
        a += v;
        b += v * v;
    }
    s1[threadIdx.x] = a;
    s2[threadIdx.x] = b;
    __syncthreads();
    if (threadIdx.x < 32) {
        float ta = 0.f, tb = 0.f;
#pragma unroll
        for (int j = 0; j < 8; ++j) {
            ta += s1[j * 32 + threadIdx.x];
            tb += s2[j * 32 + threadIdx.x];
        }
        atomicAdd(&stats[threadIdx.x], ta);
        atomicAdd(&stats[32 + threadIdx.x], tb);
    }
}

extern "C" void kernel_launch(void* const* d_in, const int* in_sizes, int n_in,
                              void* d_out, int out_size, void* d_ws, size_t ws_size,
                              hipStream_t stream) {
    const int N = in_sizes[0] / DIN;
    const int E = in_sizes[2];
    const int nbuck = (N + BUCK - 1) >> BSH;  // 391 for N=100000
    const int nb256 = nbuck * CHKC;           // 100096 cells

    const float* x = (const float*)d_in[0];
    const int* ei = (const int*)d_in[1];
    const float* ew = (const float*)d_in[2];
    const int* row = ei;
    const int* col = ei + E;

    const float* Ws[4] = {(const float*)d_in[3], (const float*)d_in[5],
                          (const float*)d_in[7], (const float*)d_in[9]};
    const float* bs[4] = {(const float*)d_in[4], (const float*)d_in[6],
                          (const float*)d_in[8], (const float*)d_in[10]};
    const float* gs[3] = {(const float*)d_in[11], (const float*)d_in[13], (const float*)d_in[15]};
    const float* bes[3] = {(const float*)d_in[12], (const float*)d_in[14], (const float*)d_in[16]};

    // workspace layout, every buffer 256B-aligned (~40 MB total)
    char* wsb = (char*)d_ws;
    size_t off0 = 0;
    auto alloc = [&](size_t bytes) -> void* {
        off0 = (off0 + 255) & ~(size_t)255;
        void* p = wsb + off0;
        off0 += bytes;
        return p;
    };
    float* dinv = (float*)alloc((size_t)N * 4);
    int* rowptr = (int*)alloc((size_t)(N + 1) * 4);
    u32* esort = (u32*)alloc((size_t)E * 4);
    float* stats = (float*)alloc(192 * 4);
    int* bsum = (int*)alloc(512 * 4);
    u32* cpart2 = (u32*)alloc((size_t)(nb256 + 256) * 4);
    // RR region: hbf (6.4M, node-major) + aggS (12.8M, node-major); rec8 (E*8=25.6M)
    // aliases it — rec8 dead before gemm_din first writes hbf.
    size_t rrMin = (size_t)N * HID * 6;
    size_t rrBytes = (size_t)E * 8 > rrMin ? (size_t)E * 8 : rrMin;
    char* RR = (char*)alloc(rrBytes);
    u16* hbf = (u16*)RR;
    float* aggS = (float*)(RR + (size_t)N * HID * 2);
    u64* rec8 = (u64*)RR;

    const int B = 256;
    const int nodeGrid32 = (N + 31) / 32;
    const int nodeGrid64 = (N + 63) / 64;
    const int scanB = (nb256 + 255) / 256;  // 392 <= 512
    const float invN = 1.0f / (float)N;

    // ---- build CSR + norm: LDS counting sort, all global writes coalesced ----
    init_stats<<<1, 256, 0, stream>>>(stats);
    bucket_count<<<CHKC, 1024, 0, stream>>>(col, E, cpart2, nbuck);
    scan_blocks<<<scanB, 256, 0, stream>>>((int*)cpart2, bsum, nb256);
    scan_tops<<<1, 512, 0, stream>>>(bsum, scanB);
    scan_addback<<<scanB + 1, 256, 0, stream>>>((int*)cpart2, bsum, nb256, E);
    bucket_scatter<<<CHKC, 1024, 0, stream>>>(row, col, ew, cpart2, rec8, E, nbuck);
    bucket_finalize<<<nbuck, 1024, 0, stream>>>(rec8, cpart2, rowptr, dinv, esort,
                                                E, N, nbuck);
    gemm_din<<<nodeGrid32, 256, 0, stream>>>(x, Ws[0], dinv, hbf, N);  // rec8 now dead

    // ---- layers: gemm (l>0) -> fused full-width gather -> bn_reduce ----
    for (int l = 0; l < 4; ++l) {
        if (l > 0)
            gemm_hid_bn<<<nodeGrid32, 256, 0, stream>>>(aggS, Ws[l], stats + 64 * (l - 1),
                                                        gs[l - 1], bes[l - 1], dinv,
                                                        hbf, N, invN);
        if (l < 3) {
            gather_t<0><<<nodeGrid64, B, 0, stream>>>((const u32*)hbf, rowptr, esort,
                                                      dinv, bs[l], aggS, N);
            bn_reduce<<<512, B, 0, stream>>>(aggS, stats + 64 * l, N);
        } else {
            // final layer: gather + ReLU straight to d_out
            gather_t<1><<<nodeGrid64, B, 0, stream>>>((const u32*)hbf, rowptr, esort,
                                                      dinv, bs[l], (float*)d_out, N);
        }
    }
}

// Round 13
// 485.908 us; speedup vs baseline: 1.0232x; 1.0232x over previous
//
#include <hip/hip_runtime.h>
#include <hip/hip_bf16.h>

#define DIN 128
#define HID 32
#define EPS 1e-5f
#define BUCK 256          // nodes per bucket
#define BSH 8
#define CHKC 256          // edge chunks
#define SCAP 13000        // staged records per chunk (chunk=12500 for E=3.2M)
#define RCAP 12288        // staged esort entries per bucket (mean 8192, +45 sigma)
#define WSC 16384.0f      // 2^14 fixed-point scale for w sums
#define WSI 6.103515625e-5f  // 2^-14

typedef unsigned int u32;
typedef unsigned short u16;
typedef unsigned long long u64;

// extract bf16 half of a packed u32 (hi=0 -> low 16 bits = even channel) as float
__device__ __forceinline__ float bfx(u32 v, int hi) {
    return __uint_as_float(hi ? (v & 0xffff0000u) : (v << 16));
}

__device__ __forceinline__ u16 f2bf(float f) {
    __hip_bfloat16 h = __float2bfloat16(f);
    return *reinterpret_cast<u16*>(&h);
}

// ---------------- zero BN stats ----------------
__global__ void init_stats(float* __restrict__ stats) {
    if (threadIdx.x < 192) stats[threadIdx.x] = 0.f;
}

// ---------------- phase A: per-(chunk) LDS bucket histogram ----------------
__global__ __launch_bounds__(1024) void bucket_count(
        const int* __restrict__ col, int E, u32* __restrict__ cpart2, int nbuck) {
    __shared__ u32 cnt[512];
    int c = blockIdx.x;
    for (int i = threadIdx.x; i < 512; i += 1024) cnt[i] = 0;
    __syncthreads();
    int chunk = (E + CHKC - 1) / CHKC;
    int e0 = c * chunk, e1 = e0 + chunk;
    if (e1 > E) e1 = E;
    for (int e = e0 + threadIdx.x; e < e1; e += 1024)
        atomicAdd(&cnt[col[e] >> BSH], 1u);
    __syncthreads();
    for (int i = threadIdx.x; i < nbuck; i += 1024)
        cpart2[i * CHKC + c] = cnt[i];
}

// ---------------- exclusive scan (for the (bucket,chunk) cells) ----------------
__global__ void scan_blocks(int* __restrict__ data, int* __restrict__ bsum, int n) {
    __shared__ int s[256];
    int i = blockIdx.x * 256 + threadIdx.x;
    int v = (i < n) ? data[i] : 0;
    s[threadIdx.x] = v;
    __syncthreads();
    for (int off = 1; off < 256; off <<= 1) {
        int t = (threadIdx.x >= off) ? s[threadIdx.x - off] : 0;
        __syncthreads();
        s[threadIdx.x] += t;
        __syncthreads();
    }
    if (i < n) data[i] = s[threadIdx.x] - v;  // exclusive
    if (threadIdx.x == 255) bsum[blockIdx.x] = s[255];
}

__global__ void scan_tops(int* __restrict__ bsum, int nb) {
    __shared__ int s[512];
    int v = (threadIdx.x < nb) ? bsum[threadIdx.x] : 0;
    s[threadIdx.x] = v;
    __syncthreads();
    for (int off = 1; off < 512; off <<= 1) {
        int t = (threadIdx.x >= off) ? s[threadIdx.x - off] : 0;
        __syncthreads();
        s[threadIdx.x] += t;
        __syncthreads();
    }
    if (threadIdx.x < nb) bsum[threadIdx.x] = s[threadIdx.x] - v;  // exclusive
}

__global__ void scan_addback(int* __restrict__ data, const int* __restrict__ bsum,
                             int n, int E) {
    int i = blockIdx.x * 256 + threadIdx.x;
    if (i < n) data[i] += bsum[blockIdx.x];
    if (i == n) data[n] = E;  // sentinel
}

// ---------------- phase C: LDS counting-sort scatter (all global writes coalesced) --
// record u64 = w_bits<<32 | src<<BSH | col_in_bucket.
__global__ __launch_bounds__(1024) void bucket_scatter(
        const int* __restrict__ row, const int* __restrict__ col,
        const float* __restrict__ w, const u32* __restrict__ cpart2,
        u64* __restrict__ rec8, int E, int nbuck) {
    __shared__ u64 srec[SCAP];                    // 104KB
    __shared__ u32 lcnt[512], lbase[512], lcur[512], cellb[512];
    int c = blockIdx.x, tid = threadIdx.x;
    int chunk = (E + CHKC - 1) / CHKC;
    int e0 = c * chunk, e1 = e0 + chunk;
    if (e1 > E) e1 = E;
    for (int i = tid; i < 512; i += 1024) lcnt[i] = 0;
    __syncthreads();
    if (chunk <= SCAP) {
        for (int e = e0 + tid; e < e1; e += 1024)
            atomicAdd(&lcnt[col[e] >> BSH], 1u);
        __syncthreads();
        if (tid < 512) lbase[tid] = lcnt[tid];
        __syncthreads();
        for (int off = 1; off < 512; off <<= 1) {
            u32 t = 0;
            if (tid < 512 && tid >= off) t = lbase[tid - off];
            __syncthreads();
            if (tid < 512) lbase[tid] += t;
            __syncthreads();
        }
        if (tid < 512) {
            lcur[tid] = lbase[tid] - lcnt[tid];  // exclusive base
            cellb[tid] = (tid < nbuck) ? cpart2[tid * CHKC + c] : 0;
        }
        __syncthreads();
        for (int e = e0 + tid; e < e1; e += 1024) {
            int cc = col[e];
            int b = cc >> BSH;
            u32 p = atomicAdd(&lcur[b], 1u);
            srec[p] = ((u64)__float_as_uint(w[e]) << 32) |
                      ((u64)(u32)row[e] << BSH) | (u64)(u32)(cc & (BUCK - 1));
        }
        __syncthreads();
        int wv = tid >> 6, lane = tid & 63;
        for (int b = wv; b < nbuck; b += 16) {
            int len = (int)lcnt[b];
            int s = (int)(lbase[b] - lcnt[b]);
            u64* dst = rec8 + cellb[b];
            for (int j = lane; j < len; j += 64) dst[j] = srec[s + j];
        }
    } else {
        if (tid < 512) lcur[tid] = (tid < nbuck) ? cpart2[tid * CHKC + c] : 0;
        __syncthreads();
        for (int e = e0 + tid; e < e1; e += 1024) {
            int cc = col[e];
            int b = cc >> BSH;
            u32 pos = atomicAdd(&lcur[b], 1u);
            rec8[pos] = ((u64)__float_as_uint(w[e]) << 32) |
                        ((u64)(u32)row[e] << BSH) | (u64)(u32)(cc & (BUCK - 1));
        }
    }
}

// ---------------- phase D+F fused: hist -> rowptr/dinv -> rank -> esort ----------------
// Entry stores bf16(w * dinv[dst]) (dst local -> no cross-bucket read; R12 fix).
// NEW: within each row, entries are PARTITIONED by src half (src < H first), and
// midptr[g] = rowptr[g] + countA(g). This lets the gather run in two phases whose
// h2 table working set is 3.2MB each -> L2-resident grid-wide.
__global__ __launch_bounds__(1024) void bucket_finalize(
        const u64* __restrict__ rec8, const u32* __restrict__ cpart2,
        int* __restrict__ rowptr, int* __restrict__ midptr,
        float* __restrict__ dinv, u32* __restrict__ esort,
        int E, int N, int nbuck, int H) {
    __shared__ u32 stage[RCAP];   // 48KB
    __shared__ u64 cw[BUCK];      // 2KB
    __shared__ int sp[BUCK];
    __shared__ u32 cA[BUCK];      // count of src<H per dst
    __shared__ u32 cntA[BUCK], cntB[BUCK];
    __shared__ float dl[BUCK];
    __shared__ int baseA[BUCK], baseB[BUCK];
    int b = blockIdx.x, tid = threadIdx.x;
    int k0 = (int)cpart2[b * CHKC];
    int k1 = (b + 1 < nbuck) ? (int)cpart2[(b + 1) * CHKC] : E;
    for (int i = tid; i < BUCK; i += 1024) { cw[i] = 0ull; cA[i] = 0; }
    __syncthreads();
    for (int k = k0 + tid; k < k1; k += 1024) {
        u64 v = rec8[k];
        u32 lo = (u32)v;
        int i = (int)(lo & (BUCK - 1));
        int src = (int)(lo >> BSH);
        float wv = __uint_as_float((u32)(v >> 32));
        atomicAdd(&cw[i], (1ull << 32) | (u64)(u32)(wv * WSC + 0.5f));
        if (src < H) atomicAdd(&cA[i], 1u);
    }
    __syncthreads();
    if (tid < BUCK) sp[tid] = (int)(cw[tid] >> 32);
    __syncthreads();
    for (int off = 1; off < BUCK; off <<= 1) {
        int t = 0;
        if (tid < BUCK && tid >= off) t = sp[tid - off];
        __syncthreads();
        if (tid < BUCK) sp[tid] += t;
        __syncthreads();
    }
    if (tid < BUCK) {
        int g = (b << BSH) + tid;
        int own = (int)(cw[tid] >> 32);
        float dv = rsqrtf(1.0f + (float)(u32)cw[tid] * WSI);  // +1 self loop
        int bA = sp[tid] - own;
        cntA[tid] = 0;
        cntB[tid] = 0;
        baseA[tid] = bA;
        baseB[tid] = bA + (int)cA[tid];
        dl[tid] = dv;
        if (g < N) {
            rowptr[g] = k0 + bA;
            midptr[g] = k0 + bA + (int)cA[tid];
            dinv[g] = dv;
        }
    }
    if (b == nbuck - 1 && tid == 0) rowptr[N] = E;
    __syncthreads();
    for (int k = k0 + tid; k < k1; k += 1024) {
        u64 v = rec8[k];  // L2-hot re-read
        u32 lo = (u32)v;
        int i = (int)(lo & (BUCK - 1));
        int src = (int)(lo >> BSH);
        float nv = __uint_as_float((u32)(v >> 32)) * dl[i];  // w * dinv[dst]
        u32 entry = ((u32)src << 15) | (u32)f2bf(nv);
        int off;
        if (src < H) off = baseA[i] + (int)atomicAdd(&cntA[i], 1u);
        else         off = baseB[i] + (int)atomicAdd(&cntB[i], 1u);
        if (off < RCAP) stage[off] = entry;
        else esort[k0 + off] = entry;  // overflow guard (statistically unreachable)
    }
    __syncthreads();
    int len = k1 - k0;
    int lim = len < RCAP ? len : RCAP;
    for (int j = tid; j < lim; j += 1024) esort[k0 + j] = stage[j];
}

// ---------------- layer-0 GEMM (x fp32 -> hbf = dinv[node] * (x@W), node-major) -----
__global__ __launch_bounds__(256) void gemm_din(const float* __restrict__ x,
                                                const float* __restrict__ W,
                                                const float* __restrict__ dinv,
                                                u16* __restrict__ hbf, int n) {
    __shared__ float xl[32][132];
    __shared__ float Wl[DIN * HID];  // k-major
    int t = threadIdx.x;
    for (int i = t; i < DIN * HID; i += 256) Wl[i] = W[i];
    int nbase = blockIdx.x * 32;
    int nrows = n - nbase; if (nrows > 32) nrows = 32;
    for (int i = t; i < nrows * 32; i += 256) {
        int nn = i >> 5, k4 = (i & 31) * 4;
        *(float4*)&xl[nn][k4] = *(const float4*)&x[(size_t)(nbase + nn) * DIN + k4];
    }
    __syncthreads();
    int chq = t & 7, nn = t >> 3;
    if (nn >= nrows) return;
    float ax = 0.f, ay = 0.f, az = 0.f, aw = 0.f;
#pragma unroll 8
    for (int k = 0; k < DIN; ++k) {
        float xv = xl[nn][k];
        float4 wv = *(float4*)&Wl[k * HID + chq * 4];
        ax += xv * wv.x; ay += xv * wv.y; az += xv * wv.z; aw += xv * wv.w;
    }
    int node = nbase + nn;
    float dv = dinv[node];
    ax *= dv; ay *= dv; az *= dv; aw *= dv;
    u64 pk = (u64)f2bf(ax) | ((u64)f2bf(ay) << 16) | ((u64)f2bf(az) << 32) |
             ((u64)f2bf(aw) << 48);
    *(u64*)&hbf[(size_t)node * 32 + chq * 4] = pk;
}

// ---------------- hidden GEMM, fused BN+ReLU; hbf = dinv * (relu(bn(agg))@W) --------
__global__ __launch_bounds__(256) void gemm_hid_bn(
        const float* __restrict__ aS, const float* __restrict__ W,
        const float* __restrict__ stats, const float* __restrict__ g,
        const float* __restrict__ be, const float* __restrict__ dinv,
        u16* __restrict__ hbf, int n, float invN) {
    __shared__ float xl[32][36];
    __shared__ float Wl[HID * HID];  // k-major
    __shared__ float sc[HID], sh[HID];
    int t = threadIdx.x;
    for (int i = t; i < HID * HID; i += 256) Wl[i] = W[i];
    if (t < HID) {
        float mu = stats[t] * invN;
        float var = stats[32 + t] * invN - mu * mu;
        float s = rsqrtf(var + EPS) * g[t];
        sc[t] = s;
        sh[t] = be[t] - mu * s;
    }
    int nbase = blockIdx.x * 32;
    int nrows = n - nbase; if (nrows > 32) nrows = 32;
    for (int i = t; i < nrows * 8; i += 256) {
        int nn = i >> 3, q = i & 7;
        *(float4*)&xl[nn][q * 4] =
            *(const float4*)&aS[(size_t)(nbase + nn) * 32 + q * 4];
    }
    __syncthreads();
    int chq = t & 7, nn = t >> 3;
    if (nn >= nrows) return;
    float ax = 0.f, ay = 0.f, az = 0.f, aw = 0.f;
#pragma unroll
    for (int k = 0; k < HID; ++k) {
        float v = fmaxf(xl[nn][k] * sc[k] + sh[k], 0.f);
        float4 wv = *(float4*)&Wl[k * HID + chq * 4];
        ax += v * wv.x; ay += v * wv.y; az += v * wv.z; aw += v * wv.w;
    }
    int node = nbase + nn;
    float dv = dinv[node];
    ax *= dv; ay *= dv; az *= dv; aw *= dv;
    u64 pk = (u64)f2bf(ax) | ((u64)f2bf(ay) << 16) | ((u64)f2bf(az) << 32) |
             ((u64)f2bf(aw) << 48);
    *(u64*)&hbf[(size_t)node * 32 + chq * 4] = pk;
}

// ---------------- phase-split CSR gather (v2 shape: 8 lanes/node, uint2) ------------
// PHASE 0: j in [rowptr, midptr) — all srcs < H  -> h2[0..H) = 3.2MB, L2-resident.
//          acc starts from self-term + bias; writes partial to out.
// PHASE 1: j in [midptr, rowptr+1) — srcs >= H  -> other 3.2MB half resident.
//          acc starts from out (partial); RELU optionally fused; writes out.
template<int PHASE, int RELU>
__global__ __launch_bounds__(256) void gather_t(
        const u32* __restrict__ h2, const int* __restrict__ rowptr,
        const int* __restrict__ midptr, const u32* __restrict__ esort,
        const float* __restrict__ dinv, const float* __restrict__ b,
        const float* __restrict__ prev, float* __restrict__ out, int n) {
    int q = threadIdx.x & 7;
    int node = blockIdx.x * 32 + (threadIdx.x >> 3);
    if (node >= n) return;
    float acc[4];
    int j, end;
    if (PHASE == 0) {
        float s = dinv[node];   // hbf already carries one dinv factor
        uint2 hv = *(const uint2*)&h2[(size_t)node * 16 + q * 2];
        acc[0] = s * bfx(hv.x, 0) + b[q * 4 + 0];
        acc[1] = s * bfx(hv.x, 1) + b[q * 4 + 1];
        acc[2] = s * bfx(hv.y, 0) + b[q * 4 + 2];
        acc[3] = s * bfx(hv.y, 1) + b[q * 4 + 3];
        j = rowptr[node];
        end = midptr[node];
    } else {
        float4 pv = *(const float4*)&prev[(size_t)node * 32 + q * 4];
        acc[0] = pv.x; acc[1] = pv.y; acc[2] = pv.z; acc[3] = pv.w;
        j = midptr[node];
        end = rowptr[node + 1];
    }
    for (; j + 4 <= end; j += 4) {
        u32 e0 = esort[j], e1 = esort[j + 1], e2 = esort[j + 2], e3 = esort[j + 3];
        uint2 v0 = *(const uint2*)&h2[(size_t)(e0 >> 15) * 16 + q * 2];
        uint2 v1 = *(const uint2*)&h2[(size_t)(e1 >> 15) * 16 + q * 2];
        uint2 v2 = *(const uint2*)&h2[(size_t)(e2 >> 15) * 16 + q * 2];
        uint2 v3 = *(const uint2*)&h2[(size_t)(e3 >> 15) * 16 + q * 2];
        float n0 = __uint_as_float((e0 & 0x7fffu) << 16);
        float n1 = __uint_as_float((e1 & 0x7fffu) << 16);
        float n2 = __uint_as_float((e2 & 0x7fffu) << 16);
        float n3 = __uint_as_float((e3 & 0x7fffu) << 16);
        acc[0] += n0 * bfx(v0.x, 0); acc[1] += n0 * bfx(v0.x, 1);
        acc[2] += n0 * bfx(v0.y, 0); acc[3] += n0 * bfx(v0.y, 1);
        acc[0] += n1 * bfx(v1.x, 0); acc[1] += n1 * bfx(v1.x, 1);
        acc[2] += n1 * bfx(v1.y, 0); acc[3] += n1 * bfx(v1.y, 1);
        acc[0] += n2 * bfx(v2.x, 0); acc[1] += n2 * bfx(v2.x, 1);
        acc[2] += n2 * bfx(v2.y, 0); acc[3] += n2 * bfx(v2.y, 1);
        acc[0] += n3 * bfx(v3.x, 0); acc[1] += n3 * bfx(v3.x, 1);
        acc[2] += n3 * bfx(v3.y, 0); acc[3] += n3 * bfx(v3.y, 1);
    }
    for (; j < end; ++j) {
        u32 ed = esort[j];
        uint2 v = *(const uint2*)&h2[(size_t)(ed >> 15) * 16 + q * 2];
        float nv = __uint_as_float((ed & 0x7fffu) << 16);
        acc[0] += nv * bfx(v.x, 0); acc[1] += nv * bfx(v.x, 1);
        acc[2] += nv * bfx(v.y, 0); acc[3] += nv * bfx(v.y, 1);
    }
    if (RELU) {
#pragma unroll
        for (int i = 0; i < 4; ++i) acc[i] = fmaxf(acc[i], 0.f);
    }
    float4 o = {acc[0], acc[1], acc[2], acc[3]};
    *(float4*)&out[(size_t)node * 32 + q * 4] = o;
}

// ---------------- BN stats reduce (node-major agg) ----------------
__global__ void bn_reduce(const float* __restrict__ aS, float* __restrict__ stats, int n) {
    __shared__ float s1[256], s2[256];
    int ch = threadIdx.x & 31, rg = threadIdx.x >> 5;
    float a = 0.f, b = 0.f;
    for (int node = blockIdx.x * 8 + rg; node < n; node += gridDim.x * 8) {
        float v = aS[(size_t)node * 32 + ch];
        a += v;
        b += v * v;
    }
    s1[threadIdx.x] = a;
    s2[threadIdx.x] = b;
    __syncthreads();
    if (threadIdx.x < 32) {
        float ta = 0.f, tb = 0.f;
#pragma unroll
        for (int j = 0; j < 8; ++j) {
            ta += s1[j * 32 + threadIdx.x];
            tb += s2[j * 32 + threadIdx.x];
        }
        atomicAdd(&stats[threadIdx.x], ta);
        atomicAdd(&stats[32 + threadIdx.x], tb);
    }
}

extern "C" void kernel_launch(void* const* d_in, const int* in_sizes, int n_in,
                              void* d_out, int out_size, void* d_ws, size_t ws_size,
                              hipStream_t stream) {
    const int N = in_sizes[0] / DIN;
    const int E = in_sizes[2];
    const int nbuck = (N + BUCK - 1) >> BSH;  // 391 for N=100000
    const int nb256 = nbuck * CHKC;           // 100096 cells
    const int H = N / 2;

    const float* x = (const float*)d_in[0];
    const int* ei = (const int*)d_in[1];
    const float* ew = (const float*)d_in[2];
    const int* row = ei;
    const int* col = ei + E;

    const float* Ws[4] = {(const float*)d_in[3], (const float*)d_in[5],
                          (const float*)d_in[7], (const float*)d_in[9]};
    const float* bs[4] = {(const float*)d_in[4], (const float*)d_in[6],
                          (const float*)d_in[8], (const float*)d_in[10]};
    const float* gs[3] = {(const float*)d_in[11], (const float*)d_in[13], (const float*)d_in[15]};
    const float* bes[3] = {(const float*)d_in[12], (const float*)d_in[14], (const float*)d_in[16]};

    // workspace layout, every buffer 256B-aligned (~41 MB total)
    char* wsb = (char*)d_ws;
    size_t off0 = 0;
    auto alloc = [&](size_t bytes) -> void* {
        off0 = (off0 + 255) & ~(size_t)255;
        void* p = wsb + off0;
        off0 += bytes;
        return p;
    };
    float* dinv = (float*)alloc((size_t)N * 4);
    int* rowptr = (int*)alloc((size_t)(N + 1) * 4);
    int* midptr = (int*)alloc((size_t)N * 4);
    u32* esort = (u32*)alloc((size_t)E * 4);
    float* stats = (float*)alloc(192 * 4);
    int* bsum = (int*)alloc(512 * 4);
    u32* cpart2 = (u32*)alloc((size_t)(nb256 + 256) * 4);
    // RR region: hbf (6.4M, node-major) + aggS (12.8M, node-major); rec8 (E*8=25.6M)
    // aliases it — rec8 dead before gemm_din first writes hbf.
    size_t rrMin = (size_t)N * HID * 6;
    size_t rrBytes = (size_t)E * 8 > rrMin ? (size_t)E * 8 : rrMin;
    char* RR = (char*)alloc(rrBytes);
    u16* hbf = (u16*)RR;
    float* aggS = (float*)(RR + (size_t)N * HID * 2);
    u64* rec8 = (u64*)RR;

    const int B = 256;
    const int nodeGrid32 = (N + 31) / 32;   // 3125 blocks = 12.2/CU
    const int scanB = (nb256 + 255) / 256;  // 392 <= 512
    const float invN = 1.0f / (float)N;

    // ---- build CSR + norm: LDS counting sort, src-half row partition ----
    init_stats<<<1, 256, 0, stream>>>(stats);
    bucket_count<<<CHKC, 1024, 0, stream>>>(col, E, cpart2, nbuck);
    scan_blocks<<<scanB, 256, 0, stream>>>((int*)cpart2, bsum, nb256);
    scan_tops<<<1, 512, 0, stream>>>(bsum, scanB);
    scan_addback<<<scanB + 1, 256, 0, stream>>>((int*)cpart2, bsum, nb256, E);
    bucket_scatter<<<CHKC, 1024, 0, stream>>>(row, col, ew, cpart2, rec8, E, nbuck);
    bucket_finalize<<<nbuck, 1024, 0, stream>>>(rec8, cpart2, rowptr, midptr, dinv,
                                                esort, E, N, nbuck, H);
    gemm_din<<<nodeGrid32, 256, 0, stream>>>(x, Ws[0], dinv, hbf, N);  // rec8 now dead

    // ---- layers: gemm (l>0) -> gatherA (half A resident) -> gatherB -> bn ----
    for (int l = 0; l < 4; ++l) {
        if (l > 0)
            gemm_hid_bn<<<nodeGrid32, 256, 0, stream>>>(aggS, Ws[l], stats + 64 * (l - 1),
                                                        gs[l - 1], bes[l - 1], dinv,
                                                        hbf, N, invN);
        if (l < 3) {
            gather_t<0, 0><<<nodeGrid32, B, 0, stream>>>((const u32*)hbf, rowptr, midptr,
                                                         esort, dinv, bs[l], nullptr,
                                                         aggS, N);
            gather_t<1, 0><<<nodeGrid32, B, 0, stream>>>((const u32*)hbf, rowptr, midptr,
                                                         esort, dinv, bs[l], aggS,
                                                         aggS, N);
            bn_reduce<<<512, B, 0, stream>>>(aggS, stats + 64 * l, N);
        } else {
            gather_t<0, 0><<<nodeGrid32, B, 0, stream>>>((const u32*)hbf, rowptr, midptr,
                                                         esort, dinv, bs[l], nullptr,
                                                         aggS, N);
            gather_t<1, 1><<<nodeGrid32, B, 0, stream>>>((const u32*)hbf, rowptr, midptr,
                                                         esort, dinv, bs[l], aggS,
                                                         (float*)d_out, N);
        }
    }
}

// Round 14
// 458.133 us; speedup vs baseline: 1.0853x; 1.0606x over previous
//
#include <hip/hip_runtime.h>
#include <hip/hip_bf16.h>

#define DIN 128
#define HID 32
#define EPS 1e-5f
#define BUCK 256          // nodes per bucket
#define BSH 8
#define CHKC 256          // edge chunks
#define SCAP 13000        // staged records per chunk (chunk=12500 for E=3.2M)
#define RCAP 12288        // staged esort entries per bucket (mean 8192, +45 sigma)
#define WSC 16384.0f      // 2^14 fixed-point scale for w sums
#define WSI 6.103515625e-5f  // 2^-14

typedef unsigned int u32;
typedef unsigned short u16;
typedef unsigned long long u64;

// extract bf16 half of a packed u32 (hi=0 -> low 16 bits = even channel) as float
__device__ __forceinline__ float bfx(u32 v, int hi) {
    return __uint_as_float(hi ? (v & 0xffff0000u) : (v << 16));
}

__device__ __forceinline__ u16 f2bf(float f) {
    __hip_bfloat16 h = __float2bfloat16(f);
    return *reinterpret_cast<u16*>(&h);
}

// ---------------- zero BN stats ----------------
__global__ void init_stats(float* __restrict__ stats) {
    if (threadIdx.x < 192) stats[threadIdx.x] = 0.f;
}

// ---------------- phase A: per-(chunk) LDS bucket histogram ----------------
__global__ __launch_bounds__(1024) void bucket_count(
        const int* __restrict__ col, int E, u32* __restrict__ cpart2, int nbuck) {
    __shared__ u32 cnt[512];
    int c = blockIdx.x;
    for (int i = threadIdx.x; i < 512; i += 1024) cnt[i] = 0;
    __syncthreads();
    int chunk = (E + CHKC - 1) / CHKC;
    int e0 = c * chunk, e1 = e0 + chunk;
    if (e1 > E) e1 = E;
    for (int e = e0 + threadIdx.x; e < e1; e += 1024)
        atomicAdd(&cnt[col[e] >> BSH], 1u);
    __syncthreads();
    for (int i = threadIdx.x; i < nbuck; i += 1024)
        cpart2[i * CHKC + c] = cnt[i];
}

// ---------------- exclusive scan (for the (bucket,chunk) cells) ----------------
__global__ void scan_blocks(int* __restrict__ data, int* __restrict__ bsum, int n) {
    __shared__ int s[256];
    int i = blockIdx.x * 256 + threadIdx.x;
    int v = (i < n) ? data[i] : 0;
    s[threadIdx.x] = v;
    __syncthreads();
    for (int off = 1; off < 256; off <<= 1) {
        int t = (threadIdx.x >= off) ? s[threadIdx.x - off] : 0;
        __syncthreads();
        s[threadIdx.x] += t;
        __syncthreads();
    }
    if (i < n) data[i] = s[threadIdx.x] - v;  // exclusive
    if (threadIdx.x == 255) bsum[blockIdx.x] = s[255];
}

__global__ void scan_tops(int* __restrict__ bsum, int nb) {
    __shared__ int s[512];
    int v = (threadIdx.x < nb) ? bsum[threadIdx.x] : 0;
    s[threadIdx.x] = v;
    __syncthreads();
    for (int off = 1; off < 512; off <<= 1) {
        int t = (threadIdx.x >= off) ? s[threadIdx.x - off] : 0;
        __syncthreads();
        s[threadIdx.x] += t;
        __syncthreads();
    }
    if (threadIdx.x < nb) bsum[threadIdx.x] = s[threadIdx.x] - v;  // exclusive
}

__global__ void scan_addback(int* __restrict__ data, const int* __restrict__ bsum,
                             int n, int E) {
    int i = blockIdx.x * 256 + threadIdx.x;
    if (i < n) data[i] += bsum[blockIdx.x];
    if (i == n) data[n] = E;  // sentinel
}

// ---------------- phase C: LDS counting-sort scatter (all global writes coalesced) --
// record u64 = w_bits<<32 | src<<BSH | col_in_bucket.
__global__ __launch_bounds__(1024) void bucket_scatter(
        const int* __restrict__ row, const int* __restrict__ col,
        const float* __restrict__ w, const u32* __restrict__ cpart2,
        u64* __restrict__ rec8, int E, int nbuck) {
    __shared__ u64 srec[SCAP];                    // 104KB
    __shared__ u32 lcnt[512], lbase[512], lcur[512], cellb[512];
    int c = blockIdx.x, tid = threadIdx.x;
    int chunk = (E + CHKC - 1) / CHKC;
    int e0 = c * chunk, e1 = e0 + chunk;
    if (e1 > E) e1 = E;
    for (int i = tid; i < 512; i += 1024) lcnt[i] = 0;
    __syncthreads();
    if (chunk <= SCAP) {
        for (int e = e0 + tid; e < e1; e += 1024)
            atomicAdd(&lcnt[col[e] >> BSH], 1u);
        __syncthreads();
        if (tid < 512) lbase[tid] = lcnt[tid];
        __syncthreads();
        for (int off = 1; off < 512; off <<= 1) {
            u32 t = 0;
            if (tid < 512 && tid >= off) t = lbase[tid - off];
            __syncthreads();
            if (tid < 512) lbase[tid] += t;
            __syncthreads();
        }
        if (tid < 512) {
            lcur[tid] = lbase[tid] - lcnt[tid];  // exclusive base
            cellb[tid] = (tid < nbuck) ? cpart2[tid * CHKC + c] : 0;
        }
        __syncthreads();
        for (int e = e0 + tid; e < e1; e += 1024) {
            int cc = col[e];
            int b = cc >> BSH;
            u32 p = atomicAdd(&lcur[b], 1u);
            srec[p] = ((u64)__float_as_uint(w[e]) << 32) |
                      ((u64)(u32)row[e] << BSH) | (u64)(u32)(cc & (BUCK - 1));
        }
        __syncthreads();
        int wv = tid >> 6, lane = tid & 63;
        for (int b = wv; b < nbuck; b += 16) {
            int len = (int)lcnt[b];
            int s = (int)(lbase[b] - lcnt[b]);
            u64* dst = rec8 + cellb[b];
            for (int j = lane; j < len; j += 64) dst[j] = srec[s + j];
        }
    } else {
        if (tid < 512) lcur[tid] = (tid < nbuck) ? cpart2[tid * CHKC + c] : 0;
        __syncthreads();
        for (int e = e0 + tid; e < e1; e += 1024) {
            int cc = col[e];
            int b = cc >> BSH;
            u32 pos = atomicAdd(&lcur[b], 1u);
            rec8[pos] = ((u64)__float_as_uint(w[e]) << 32) |
                        ((u64)(u32)row[e] << BSH) | (u64)(u32)(cc & (BUCK - 1));
        }
    }
}

// ---------------- phase D+F fused: hist -> rowptr/dinv -> rank -> esort ----------------
// Entry stores bf16(w * dinv[dst]) (dst local -> no cross-bucket read; R12 fix).
// Rows remain partitioned by src half (harmless for the single-pass gather, which
// reads the full row [rowptr, rowptr+1)).
__global__ __launch_bounds__(1024) void bucket_finalize(
        const u64* __restrict__ rec8, const u32* __restrict__ cpart2,
        int* __restrict__ rowptr, int* __restrict__ midptr,
        float* __restrict__ dinv, u32* __restrict__ esort,
        int E, int N, int nbuck, int H) {
    __shared__ u32 stage[RCAP];   // 48KB
    __shared__ u64 cw[BUCK];      // 2KB
    __shared__ int sp[BUCK];
    __shared__ u32 cA[BUCK];      // count of src<H per dst
    __shared__ u32 cntA[BUCK], cntB[BUCK];
    __shared__ float dl[BUCK];
    __shared__ int baseA[BUCK], baseB[BUCK];
    int b = blockIdx.x, tid = threadIdx.x;
    int k0 = (int)cpart2[b * CHKC];
    int k1 = (b + 1 < nbuck) ? (int)cpart2[(b + 1) * CHKC] : E;
    for (int i = tid; i < BUCK; i += 1024) { cw[i] = 0ull; cA[i] = 0; }
    __syncthreads();
    for (int k = k0 + tid; k < k1; k += 1024) {
        u64 v = rec8[k];
        u32 lo = (u32)v;
        int i = (int)(lo & (BUCK - 1));
        int src = (int)(lo >> BSH);
        float wv = __uint_as_float((u32)(v >> 32));
        atomicAdd(&cw[i], (1ull << 32) | (u64)(u32)(wv * WSC + 0.5f));
        if (src < H) atomicAdd(&cA[i], 1u);
    }
    __syncthreads();
    if (tid < BUCK) sp[tid] = (int)(cw[tid] >> 32);
    __syncthreads();
    for (int off = 1; off < BUCK; off <<= 1) {
        int t = 0;
        if (tid < BUCK && tid >= off) t = sp[tid - off];
        __syncthreads();
        if (tid < BUCK) sp[tid] += t;
        __syncthreads();
    }
    if (tid < BUCK) {
        int g = (b << BSH) + tid;
        int own = (int)(cw[tid] >> 32);
        float dv = rsqrtf(1.0f + (float)(u32)cw[tid] * WSI);  // +1 self loop
        int bA = sp[tid] - own;
        cntA[tid] = 0;
        cntB[tid] = 0;
        baseA[tid] = bA;
        baseB[tid] = bA + (int)cA[tid];
        dl[tid] = dv;
        if (g < N) {
            rowptr[g] = k0 + bA;
            midptr[g] = k0 + bA + (int)cA[tid];
            dinv[g] = dv;
        }
    }
    if (b == nbuck - 1 && tid == 0) rowptr[N] = E;
    __syncthreads();
    for (int k = k0 + tid; k < k1; k += 1024) {
        u64 v = rec8[k];  // L2-hot re-read
        u32 lo = (u32)v;
        int i = (int)(lo & (BUCK - 1));
        int src = (int)(lo >> BSH);
        float nv = __uint_as_float((u32)(v >> 32)) * dl[i];  // w * dinv[dst]
        u32 entry = ((u32)src << 15) | (u32)f2bf(nv);
        int off;
        if (src < H) off = baseA[i] + (int)atomicAdd(&cntA[i], 1u);
        else         off = baseB[i] + (int)atomicAdd(&cntB[i], 1u);
        if (off < RCAP) stage[off] = entry;
        else esort[k0 + off] = entry;  // overflow guard (statistically unreachable)
    }
    __syncthreads();
    int len = k1 - k0;
    int lim = len < RCAP ? len : RCAP;
    for (int j = tid; j < lim; j += 1024) esort[k0 + j] = stage[j];
}

// ---------------- layer-0 GEMM (x fp32 -> hbf = dinv[node] * (x@W), node-major) -----
__global__ __launch_bounds__(256) void gemm_din(const float* __restrict__ x,
                                                const float* __restrict__ W,
                                                const float* __restrict__ dinv,
                                                u16* __restrict__ hbf, int n) {
    __shared__ float xl[32][132];
    __shared__ float Wl[DIN * HID];  // k-major
    int t = threadIdx.x;
    for (int i = t; i < DIN * HID; i += 256) Wl[i] = W[i];
    int nbase = blockIdx.x * 32;
    int nrows = n - nbase; if (nrows > 32) nrows = 32;
    for (int i = t; i < nrows * 32; i += 256) {
        int nn = i >> 5, k4 = (i & 31) * 4;
        *(float4*)&xl[nn][k4] = *(const float4*)&x[(size_t)(nbase + nn) * DIN + k4];
    }
    __syncthreads();
    int chq = t & 7, nn = t >> 3;
    if (nn >= nrows) return;
    float ax = 0.f, ay = 0.f, az = 0.f, aw = 0.f;
#pragma unroll 8
    for (int k = 0; k < DIN; ++k) {
        float xv = xl[nn][k];
        float4 wv = *(float4*)&Wl[k * HID + chq * 4];
        ax += xv * wv.x; ay += xv * wv.y; az += xv * wv.z; aw += xv * wv.w;
    }
    int node = nbase + nn;
    float dv = dinv[node];
    ax *= dv; ay *= dv; az *= dv; aw *= dv;
    u64 pk = (u64)f2bf(ax) | ((u64)f2bf(ay) << 16) | ((u64)f2bf(az) << 32) |
             ((u64)f2bf(aw) << 48);
    *(u64*)&hbf[(size_t)node * 32 + chq * 4] = pk;
}

// ---------------- hidden GEMM, fused BN+ReLU; hbf = dinv * (relu(bn(agg))@W) --------
__global__ __launch_bounds__(256) void gemm_hid_bn(
        const float* __restrict__ aS, const float* __restrict__ W,
        const float* __restrict__ stats, const float* __restrict__ g,
        const float* __restrict__ be, const float* __restrict__ dinv,
        u16* __restrict__ hbf, int n, float invN) {
    __shared__ float xl[32][36];
    __shared__ float Wl[HID * HID];  // k-major
    __shared__ float sc[HID], sh[HID];
    int t = threadIdx.x;
    for (int i = t; i < HID * HID; i += 256) Wl[i] = W[i];
    if (t < HID) {
        float mu = stats[t] * invN;
        float var = stats[32 + t] * invN - mu * mu;
        float s = rsqrtf(var + EPS) * g[t];
        sc[t] = s;
        sh[t] = be[t] - mu * s;
    }
    int nbase = blockIdx.x * 32;
    int nrows = n - nbase; if (nrows > 32) nrows = 32;
    for (int i = t; i < nrows * 8; i += 256) {
        int nn = i >> 3, q = i & 7;
        *(float4*)&xl[nn][q * 4] =
            *(const float4*)&aS[(size_t)(nbase + nn) * 32 + q * 4];
    }
    __syncthreads();
    int chq = t & 7, nn = t >> 3;
    if (nn >= nrows) return;
    float ax = 0.f, ay = 0.f, az = 0.f, aw = 0.f;
#pragma unroll
    for (int k = 0; k < HID; ++k) {
        float v = fmaxf(xl[nn][k] * sc[k] + sh[k], 0.f);
        float4 wv = *(float4*)&Wl[k * HID + chq * 4];
        ax += v * wv.x; ay += v * wv.y; az += v * wv.z; aw += v * wv.w;
    }
    int node = nbase + nn;
    float dv = dinv[node];
    ax *= dv; ay *= dv; az *= dv; aw *= dv;
    u64 pk = (u64)f2bf(ax) | ((u64)f2bf(ay) << 16) | ((u64)f2bf(az) << 32) |
             ((u64)f2bf(aw) << 48);
    *(u64*)&hbf[(size_t)node * 32 + chq * 4] = pk;
}

// ---------------- single-pass CSR gather, v4: 8-deep batched loads ----------------
// 8 lanes/node (uint2/edge). Row loop batches 8 edges: load 8 contiguous esort
// entries into regs (L1/L2 hits), then issue all 8 independent h2 loads together
// -> 8 outstanding table misses per wave (v2 had ~4). RELU fuses the final ReLU.
template<int RELU>
__global__ __launch_bounds__(256) void gather_t(
        const u32* __restrict__ h2, const int* __restrict__ rowptr,
        const u32* __restrict__ esort, const float* __restrict__ dinv,
        const float* __restrict__ b, float* __restrict__ out, int n) {
    int q = threadIdx.x & 7;
    int node = blockIdx.x * 32 + (threadIdx.x >> 3);
    if (node >= n) return;
    float s = dinv[node];   // hbf already carries one dinv factor
    uint2 hv = *(const uint2*)&h2[(size_t)node * 16 + q * 2];
    float acc[4];
    acc[0] = s * bfx(hv.x, 0) + b[q * 4 + 0];
    acc[1] = s * bfx(hv.x, 1) + b[q * 4 + 1];
    acc[2] = s * bfx(hv.y, 0) + b[q * 4 + 2];
    acc[3] = s * bfx(hv.y, 1) + b[q * 4 + 3];
    int j = rowptr[node], end = rowptr[node + 1];
    for (; j + 8 <= end; j += 8) {
        u32 em[8];
#pragma unroll
        for (int u = 0; u < 8; ++u) em[u] = esort[j + u];
        uint2 v[8];
#pragma unroll
        for (int u = 0; u < 8; ++u)
            v[u] = *(const uint2*)&h2[(size_t)(em[u] >> 15) * 16 + q * 2];
#pragma unroll
        for (int u = 0; u < 8; ++u) {
            float nv = __uint_as_float((em[u] & 0x7fffu) << 16);
            acc[0] += nv * bfx(v[u].x, 0);
            acc[1] += nv * bfx(v[u].x, 1);
            acc[2] += nv * bfx(v[u].y, 0);
            acc[3] += nv * bfx(v[u].y, 1);
        }
    }
    if (j + 4 <= end) {
        u32 em[4];
#pragma unroll
        for (int u = 0; u < 4; ++u) em[u] = esort[j + u];
        uint2 v[4];
#pragma unroll
        for (int u = 0; u < 4; ++u)
            v[u] = *(const uint2*)&h2[(size_t)(em[u] >> 15) * 16 + q * 2];
#pragma unroll
        for (int u = 0; u < 4; ++u) {
            float nv = __uint_as_float((em[u] & 0x7fffu) << 16);
            acc[0] += nv * bfx(v[u].x, 0);
            acc[1] += nv * bfx(v[u].x, 1);
            acc[2] += nv * bfx(v[u].y, 0);
            acc[3] += nv * bfx(v[u].y, 1);
        }
        j += 4;
    }
    for (; j < end; ++j) {
        u32 ed = esort[j];
        uint2 v = *(const uint2*)&h2[(size_t)(ed >> 15) * 16 + q * 2];
        float nv = __uint_as_float((ed & 0x7fffu) << 16);
        acc[0] += nv * bfx(v.x, 0);
        acc[1] += nv * bfx(v.x, 1);
        acc[2] += nv * bfx(v.y, 0);
        acc[3] += nv * bfx(v.y, 1);
    }
    if (RELU) {
#pragma unroll
        for (int i = 0; i < 4; ++i) acc[i] = fmaxf(acc[i], 0.f);
    }
    float4 o = {acc[0], acc[1], acc[2], acc[3]};
    *(float4*)&out[(size_t)node * 32 + q * 4] = o;
}

// ---------------- BN stats reduce (node-major agg) ----------------
__global__ void bn_reduce(const float* __restrict__ aS, float* __restrict__ stats, int n) {
    __shared__ float s1[256], s2[256];
    int ch = threadIdx.x & 31, rg = threadIdx.x >> 5;
    float a = 0.f, b = 0.f;
    for (int node = blockIdx.x * 8 + rg; node < n; node += gridDim.x * 8) {
        float v = aS[(size_t)node * 32 + ch];
        a += v;
        b += v * v;
    }
    s1[threadIdx.x] = a;
    s2[threadIdx.x] = b;
    __syncthreads();
    if (threadIdx.x < 32) {
        float ta = 0.f, tb = 0.f;
#pragma unroll
        for (int j = 0; j < 8; ++j) {
            ta += s1[j * 32 + threadIdx.x];
            tb += s2[j * 32 + threadIdx.x];
        }
        atomicAdd(&stats[threadIdx.x], ta);
        atomicAdd(&stats[32 + threadIdx.x], tb);
    }
}

extern "C" void kernel_launch(void* const* d_in, const int* in_sizes, int n_in,
                              void* d_out, int out_size, void* d_ws, size_t ws_size,
                              hipStream_t stream) {
    const int N = in_sizes[0] / DIN;
    const int E = in_sizes[2];
    const int nbuck = (N + BUCK - 1) >> BSH;  // 391 for N=100000
    const int nb256 = nbuck * CHKC;           // 100096 cells
    const int H = N / 2;

    const float* x = (const float*)d_in[0];
    const int* ei = (const int*)d_in[1];
    const float* ew = (const float*)d_in[2];
    const int* row = ei;
    const int* col = ei + E;

    const float* Ws[4] = {(const float*)d_in[3], (const float*)d_in[5],
                          (const float*)d_in[7], (const float*)d_in[9]};
    const float* bs[4] = {(const float*)d_in[4], (const float*)d_in[6],
                          (const float*)d_in[8], (const float*)d_in[10]};
    const float* gs[3] = {(const float*)d_in[11], (const float*)d_in[13], (const float*)d_in[15]};
    const float* bes[3] = {(const float*)d_in[12], (const float*)d_in[14], (const float*)d_in[16]};

    // workspace layout, every buffer 256B-aligned (~41 MB total)
    char* wsb = (char*)d_ws;
    size_t off0 = 0;
    auto alloc = [&](size_t bytes) -> void* {
        off0 = (off0 + 255) & ~(size_t)255;
        void* p = wsb + off0;
        off0 += bytes;
        return p;
    };
    float* dinv = (float*)alloc((size_t)N * 4);
    int* rowptr = (int*)alloc((size_t)(N + 1) * 4);
    int* midptr = (int*)alloc((size_t)N * 4);
    u32* esort = (u32*)alloc((size_t)E * 4);
    float* stats = (float*)alloc(192 * 4);
    int* bsum = (int*)alloc(512 * 4);
    u32* cpart2 = (u32*)alloc((size_t)(nb256 + 256) * 4);
    // RR region: hbf (6.4M, node-major) + aggS (12.8M, node-major); rec8 (E*8=25.6M)
    // aliases it — rec8 dead before gemm_din first writes hbf.
    size_t rrMin = (size_t)N * HID * 6;
    size_t rrBytes = (size_t)E * 8 > rrMin ? (size_t)E * 8 : rrMin;
    char* RR = (char*)alloc(rrBytes);
    u16* hbf = (u16*)RR;
    float* aggS = (float*)(RR + (size_t)N * HID * 2);
    u64* rec8 = (u64*)RR;

    const int B = 256;
    const int nodeGrid32 = (N + 31) / 32;   // 3125 blocks = 12.2/CU
    const int scanB = (nb256 + 255) / 256;  // 392 <= 512
    const float invN = 1.0f / (float)N;

    // ---- build CSR + norm: LDS counting sort, all global writes coalesced ----
    init_stats<<<1, 256, 0, stream>>>(stats);
    bucket_count<<<CHKC, 1024, 0, stream>>>(col, E, cpart2, nbuck);
    scan_blocks<<<scanB, 256, 0, stream>>>((int*)cpart2, bsum, nb256);
    scan_tops<<<1, 512, 0, stream>>>(bsum, scanB);
    scan_addback<<<scanB + 1, 256, 0, stream>>>((int*)cpart2, bsum, nb256, E);
    bucket_scatter<<<CHKC, 1024, 0, stream>>>(row, col, ew, cpart2, rec8, E, nbuck);
    bucket_finalize<<<nbuck, 1024, 0, stream>>>(rec8, cpart2, rowptr, midptr, dinv,
                                                esort, E, N, nbuck, H);
    gemm_din<<<nodeGrid32, 256, 0, stream>>>(x, Ws[0], dinv, hbf, N);  // rec8 now dead

    // ---- layers: gemm (l>0) -> single-pass deep-MLP gather -> bn_reduce ----
    for (int l = 0; l < 4; ++l) {
        if (l > 0)
            gemm_hid_bn<<<nodeGrid32, 256, 0, stream>>>(aggS, Ws[l], stats + 64 * (l - 1),
                                                        gs[l - 1], bes[l - 1], dinv,
                                                        hbf, N, invN);
        if (l < 3) {
            gather_t<0><<<nodeGrid32, B, 0, stream>>>((const u32*)hbf, rowptr, esort,
                                                      dinv, bs[l], aggS, N);
            bn_reduce<<<512, B, 0, stream>>>(aggS, stats + 64 * l, N);
        } else {
            // final layer: gather + ReLU straight to d_out
            gather_t<1><<<nodeGrid32, B, 0, stream>>>((const u32*)hbf, rowptr, esort,
                                                      dinv, bs[l], (float*)d_out, N);
        }
    }
}